// Round 8
// baseline (108.572 us; speedup 1.0000x reference)
//
#include <hip/hip_runtime.h>
#include <math.h>

// FutureEncoder: B=4, S=2048, D=1024, FUTURE_K=32, fp32 in/out.
// R11: scores rebuilt around async global_load_lds staging (the compiler
// serializes register prefetch — R1 showed VGPR=48 and 90% stall; the async
// LDS path is the only load hipcc can't fold). 49-row x 128-float K-chunks,
// double-buffered LDS, XOR-swizzled source+read (T2), 6 waves = (B-tile x
// k-pair), 1 barrier/chunk. PV kernel unchanged (streaming, static window).

constexpr int S_CONST = 2048;
constexpr int D = 1024;
constexpr int G = 16;            // tokens per scores-block
constexpr int NTOK = 8192;
constexpr int TB = 8;            // tokens per PV-block

typedef short bf16x8 __attribute__((ext_vector_type(8)));
typedef float f32x4  __attribute__((ext_vector_type(4)));
typedef unsigned int u32x4 __attribute__((ext_vector_type(4)));

// 8 fp32 -> hi/lo bf16 fragments via v_cvt_pk_bf16_f32 (RNE).
__device__ inline void cvt8(float4 x0, float4 x1, bf16x8& hi, bf16x8& lo) {
    float xs[8] = {x0.x, x0.y, x0.z, x0.w, x1.x, x1.y, x1.z, x1.w};
    u32x4 hv, lv;
    #pragma unroll
    for (int p = 0; p < 4; ++p) {
        float a = xs[2 * p], b = xs[2 * p + 1];
        unsigned hp;
        asm("v_cvt_pk_bf16_f32 %0, %1, %2" : "=v"(hp) : "v"(a), "v"(b));
        float ha = __builtin_bit_cast(float, hp << 16);
        float hb = __builtin_bit_cast(float, hp & 0xffff0000u);
        float la = a - ha, lb = b - hb;
        unsigned lp;
        asm("v_cvt_pk_bf16_f32 %0, %1, %2" : "=v"(lp) : "v"(la), "v"(lb));
        hv[p] = hp; lv[p] = lp;
    }
    hi = __builtin_bit_cast(bf16x8, hv);
    lo = __builtin_bit_cast(bf16x8, lv);
}

#if __has_builtin(__builtin_amdgcn_global_load_lds)
#define HAVE_GLDS 1
__device__ inline void gload_lds16(const float* gp, float* lp) {
    __builtin_amdgcn_global_load_lds(
        (const __attribute__((address_space(1))) void*)gp,
        (__attribute__((address_space(3))) void*)lp, 16, 0, 0);
}
#else
#define HAVE_GLDS 0
#endif

// ---------------------------------------------------------------------------
// Kernel A: banded scores + softmax -> wm[NTOK][32] (fp32, workspace).
// 384 threads = 6 waves; wave = (B-tile 0..2, k-pair 0..1).
// LDS: double-buffered 49-row x 128-float chunk, swizzled; sc partials.
// ---------------------------------------------------------------------------
__global__ __launch_bounds__(384)
void scores_kernel(const float* __restrict__ h, float* __restrict__ wmg) {
    __shared__ float buf[2][49 * 128];   // 50176 B
    __shared__ float sc6[6][16][17];     //  6528 B

    int bid = blockIdx.x, nblk = gridDim.x, lb = bid;
    if ((nblk & 7) == 0) {
        int per = nblk >> 3;
        lb = (bid & 7) * per + (bid >> 3);
    }

    const int tid  = threadIdx.x;
    const int w    = tid >> 6;          // 0..5
    const int lane = tid & 63;
    const int t0   = lb * G;
    const int s0   = t0 & (S_CONST - 1);
    const int jlim = (S_CONST - 2) - s0;

    const int tile = w >> 1;            // B-tile 0..2
    const int kp   = w & 1;             // k-step pair 0..1
    const int mq   = lane >> 4;         // quarter 0..3
    const int mr   = lane & 15;         // row-within-tile

    // ---- stage chunk c into buf[pp]: rows t0..t0+48, floats [c*128, +128) --
    // Source pre-swizzled within each 512B row-chunk: byte ^ ((row&7)<<4).
    // LDS dest linear (global_load_lds requires base + lane*16).
    auto stage = [&](int pp, int c) {
        #pragma unroll
        for (int r = 0; r < 5; ++r) {
            int s = r * 384 + w * 64 + lane;        // 16B lane-slot
            if (s < 49 * 32) {
                int row = s >> 5;
                int li  = s & 31;
                int grow = min(t0 + row, NTOK - 1);
                int swz  = ((li * 16) ^ ((row & 7) << 4)) >> 2;  // float off
                const float* gp = h + (size_t)grow * D + c * 128 + swz;
#if HAVE_GLDS
                float* lp = &buf[pp][(r * 384 + w * 64) * 4];
                gload_lds16(gp, lp);
#else
                *(float4*)&buf[pp][s * 4] = *(const float4*)gp;
#endif
            }
        }
    };

    f32x4 acc = {0, 0, 0, 0};

    stage(0, 0);
    __syncthreads();

    for (int c = 0; c < 8; ++c) {
        if (c < 7) stage((c + 1) & 1, c + 1);
        const float* bc = buf[c & 1];

        #pragma unroll
        for (int kh = 0; kh < 2; ++kh) {
            const int ks = kp * 2 + kh;             // k-substep 0..3
            const int f0 = ks * 32 + mq * 8;        // float offset in row

            // A fragment: token row mr
            const int Xa = (mr & 7) << 2;
            float4 a0 = *(const float4*)&bc[mr * 128 + ((f0)     ^ Xa)];
            float4 a1 = *(const float4*)&bc[mr * 128 + ((f0 + 4) ^ Xa)];
            bf16x8 ah, al;
            cvt8(a0, a1, ah, al);

            // B fragment: future row 1 + tile*16 + mr
            const int rb = 1 + tile * 16 + mr;
            const int Xb = (rb & 7) << 2;
            float4 b0 = *(const float4*)&bc[rb * 128 + ((f0)     ^ Xb)];
            float4 b1 = *(const float4*)&bc[rb * 128 + ((f0 + 4) ^ Xb)];
            bf16x8 bh, bl;
            cvt8(b0, b1, bh, bl);

            acc = __builtin_amdgcn_mfma_f32_16x16x32_bf16(ah, bh, acc, 0, 0, 0);
            acc = __builtin_amdgcn_mfma_f32_16x16x32_bf16(ah, bl, acc, 0, 0, 0);
            acc = __builtin_amdgcn_mfma_f32_16x16x32_bf16(al, bh, acc, 0, 0, 0);
        }
        __syncthreads();   // drains this chunk's async stage; joins waves
    }

    // C layout: col = lane&15 (j within tile), row = (lane>>4)*4 + reg (token)
    #pragma unroll
    for (int r = 0; r < 4; ++r)
        sc6[w][mq * 4 + r][mr] = acc[r];
    __syncthreads();

    // ---- reduce k-pair partials + softmax -> global wm ----------------------
    if (tid < 256) {
        const int i   = tid >> 4;      // token 0..15
        const int sub = tid & 15;      // j within tile

        float v[3];
        #pragma unroll
        for (int c = 0; c < 3; ++c) {
            int j = sub + c * 16;
            float s = sc6[c * 2 + 0][i][sub] + sc6[c * 2 + 1][i][sub];
            bool valid = (j >= i) && (j <= i + 31) && (j <= jlim);
            v[c] = valid ? s : -1e9f;
        }
        float mx = fmaxf(v[0], fmaxf(v[1], v[2]));
        #pragma unroll
        for (int d = 1; d < 16; d <<= 1) mx = fmaxf(mx, __shfl_xor(mx, d, 16));

        float e[3];
        float sum = 0.f;
        #pragma unroll
        for (int c = 0; c < 3; ++c) { e[c] = __expf(v[c] - mx); sum += e[c]; }
        #pragma unroll
        for (int d = 1; d < 16; d <<= 1) sum += __shfl_xor(sum, d, 16);

        const bool any = (mx > -5e8f);
        const float inv = any ? (1.0f / sum) : 0.f;

        float* wrow = wmg + (size_t)(t0 + i) * 32;
        #pragma unroll
        for (int c = 0; c < 3; ++c) {
            int j = sub + c * 16;
            int k = j - i;                           // future offset 0..31
            if (k >= 0 && k < 32)
                wrow[k] = (j <= jlim) ? e[c] * inv : 0.f;
        }
    }
}

// ---------------------------------------------------------------------------
// Kernel B: PV streaming. Block = 8 tokens, 256 threads (thread = 16B D-chunk
// for all 8 tokens). 39-row sliding window, fully unrolled (static indexing).
// ---------------------------------------------------------------------------
__global__ __launch_bounds__(256, 4)
void pv_kernel(const float* __restrict__ h, const float* __restrict__ wm,
               float* __restrict__ out) {
    __shared__ float lw[TB * 32];      // 8 tokens x 32 weights

    int bid = blockIdx.x, nblk = gridDim.x, lb = bid;
    if ((nblk & 7) == 0) {
        int per = nblk >> 3;
        lb = (bid & 7) * per + (bid >> 3);
    }
    const int i0   = lb * TB;
    const int tid  = threadIdx.x;
    const int doff = tid * 4;

    lw[tid] = wm[(size_t)i0 * 32 + tid];           // 256 floats, coalesced
    __syncthreads();

    float4 acc[TB] = {};
    float4 wv[TB];                                  // rolling weight quads

    #pragma unroll
    for (int rr = 0; rr < TB + 31; ++rr) {          // rows i0+1 .. i0+39
        int r = min(i0 + 1 + rr, NTOK - 1);
        float4 f = *(const float4*)(h + (size_t)r * D + doff);
        #pragma unroll
        for (int t = 0; t < TB; ++t) {
            const int k = rr - t;                   // compile-time constant
            if (k >= 0 && k < 32) {
                if ((k & 3) == 0)
                    wv[t] = *(const float4*)(&lw[t * 32 + k]);
                const float wt = ((k & 3) == 0) ? wv[t].x :
                                 ((k & 3) == 1) ? wv[t].y :
                                 ((k & 3) == 2) ? wv[t].z : wv[t].w;
                acc[t].x += wt * f.x;
                acc[t].y += wt * f.y;
                acc[t].z += wt * f.z;
                acc[t].w += wt * f.w;
            }
        }
    }

    #pragma unroll
    for (int t = 0; t < TB; ++t)
        *(float4*)(out + (size_t)(i0 + t) * D + doff) = acc[t];
}

extern "C" void kernel_launch(void* const* d_in, const int* in_sizes, int n_in,
                              void* d_out, int out_size, void* d_ws, size_t ws_size,
                              hipStream_t stream) {
    const float* h = (const float*)d_in[0];
    float* out = (float*)d_out;
    float* wm = (float*)d_ws;                      // 8192*32*4 = 1 MiB
    const int ntok = in_sizes[0] / D;              // 8192

    scores_kernel<<<ntok / G, 384, 0, stream>>>(h, wm);
    pv_kernel<<<ntok / TB, 256, 0, stream>>>(h, wm, out);
}